// Round 19
// baseline (244.408 us; speedup 1.0000x reference)
//
#include <hip/hip_runtime.h>

#define NN 50000
#define NE 800000
#define NL 200000

typedef __attribute__((ext_vector_type(8))) short bf16x8;
typedef __attribute__((ext_vector_type(4))) float f32x4;

__device__ __forceinline__ ushort bf16_rne(float f) {
    union { float f; unsigned u; } v; v.f = f;
    unsigned r = v.u + 0x7FFF + ((v.u >> 16) & 1);
    return (ushort)(r >> 16);
}
__device__ __forceinline__ float bf16_to_f(ushort h) {
    union { unsigned u; float f; } v; v.u = ((unsigned)h) << 16;
    return v.f;
}
__device__ __forceinline__ float lo_f(unsigned u) {
    union { unsigned u; float f; } v; v.u = u << 16;
    return v.f;
}
__device__ __forceinline__ float hi_f(unsigned u) {
    union { unsigned u; float f; } v; v.u = u & 0xffff0000u;
    return v.f;
}

// ---------------- fused prep: counts=0, x->bf16, W->fragment bf16 ----------------
// frag[chunk][ct][lane][j] -> W[chunk*32 + (lane>>4)*8 + j][ct*16 + (lane&15)].

template <int K, int KA, int NCAT>
__device__ __forceinline__ void wsplit_body(const float* __restrict__ W1,
                                            const float* __restrict__ W2,
                                            ushort* __restrict__ hi, int id) {
    if (id >= 128 * K) return;
    int col = id / K, k = id - col * K;
    float v;
    if constexpr (NCAT) {
        v = (col < 64) ? W1[(size_t)k * 64 + col] : W2[(size_t)k * 64 + (col - 64)];
    } else {
        v = (k < KA) ? W1[(size_t)k * 128 + col] : W2[(size_t)(k - KA) * 128 + col];
    }
    int chunk = k >> 5, kk = k & 31;
    int kg4 = kk >> 3, j = kk & 7;
    int ct = col >> 4, lr = col & 15;
    size_t dst = ((size_t)(chunk * 8 + ct) * 64 + kg4 * 16 + lr) * 8 + j;
    hi[dst] = bf16_rne(v);
}

// blocks: [0,64) W1 | [64,192) W2 | [192,256) W3 | [256,452) counts=0 | [452,2015) xcast
__global__ void k_prep(const float* __restrict__ Wl1, const float* __restrict__ Wr1,
                       const float* __restrict__ Wl2, const float* __restrict__ Wr2,
                       const float* __restrict__ Wl3, const float* __restrict__ Wr3,
                       const float* __restrict__ x,
                       ushort* __restrict__ W1h, ushort* __restrict__ W2h,
                       ushort* __restrict__ W3h, ushort* __restrict__ xb,
                       int* __restrict__ counts) {
    int b = blockIdx.x, t = threadIdx.x;
    if (b < 64) {
        wsplit_body<128, 64, 0>(Wl1, Wr1, W1h, b * 256 + t);
    } else if (b < 192) {
        wsplit_body<256, 128, 0>(Wl2, Wr2, W2h, (b - 64) * 256 + t);
    } else if (b < 256) {
        wsplit_body<128, 128, 1>(Wl3, Wr3, W3h, (b - 192) * 256 + t);
    } else if (b < 452) {
        int i = (b - 256) * 256 + t;
        if (i < NN) counts[i] = 0;
    } else {
        int i = (b - 452) * 256 + t;
        if (i >= NN * 8) return;
        float4 v0 = *(const float4*)&x[i * 8];
        float4 v1 = *(const float4*)&x[i * 8 + 4];
        ushort h[8] = {bf16_rne(v0.x), bf16_rne(v0.y), bf16_rne(v0.z), bf16_rne(v0.w),
                       bf16_rne(v1.x), bf16_rne(v1.y), bf16_rne(v1.z), bf16_rne(v1.w)};
        *(bf16x8*)&xb[i * 8] = *(bf16x8*)h;
    }
}

// ---------------- CSR build ----------------

__global__ void k_count(const int* __restrict__ tgt, int* __restrict__ counts,
                        int* __restrict__ rank) {
    int e = blockIdx.x * blockDim.x + threadIdx.x;
    if (e < NE) rank[e] = atomicAdd(&counts[tgt[e]], 1);
}

// single-workgroup scan: 1024 thr x 49 elems; LDS Hillis-Steele over thread sums.
__global__ void __launch_bounds__(1024) k_scan_one(const int* __restrict__ counts,
                                                   int* __restrict__ rowptr) {
    constexpr int VPT = 49;  // 1024*49 = 50176 >= NN
    __shared__ int s[1024];
    int t = threadIdx.x;
    int base = t * VPT;
    int loc[VPT];
    int sum = 0;
    #pragma unroll
    for (int i = 0; i < VPT; i++) {
        int idx = base + i;
        int v = (idx < NN) ? counts[idx] : 0;
        loc[i] = sum;       // local exclusive
        sum += v;
    }
    s[t] = sum;
    __syncthreads();
    for (int off = 1; off < 1024; off <<= 1) {
        int a = (t >= off) ? s[t - off] : 0;
        __syncthreads();
        s[t] += a;
        __syncthreads();
    }
    int excl = s[t] - sum;
    #pragma unroll
    for (int i = 0; i < VPT; i++) {
        int idx = base + i;
        if (idx < NN) rowptr[idx] = excl + loc[i];
    }
    if (t == 1023) rowptr[NN] = s[1023];  // == NE
}

__global__ void k_fill(const int* __restrict__ src, const int* __restrict__ tgt,
                       const int* __restrict__ rowptr, const int* __restrict__ rank,
                       int* __restrict__ csr) {
    int e = blockIdx.x * blockDim.x + threadIdx.x;
    if (e < NE) csr[rowptr[tgt[e]] + rank[e]] = src[e];
}

// ---------------- CSR gather-mean aggregation, D=64, 2-stream ----------------
// OBF=0: fp32 out. OBF=1: bf16 out (+fp32 addp first).

template <int OBF>
__global__ void k_aggb64(const ushort* __restrict__ in,
                         const float* __restrict__ addp, int addStride,
                         float* __restrict__ outF, ushort* __restrict__ outB,
                         const int* __restrict__ rowptr, const int* __restrict__ csr) {
    constexpr int D = 64, LPR = 8, EPW = 8;
    int node = blockIdx.x * 4 + (threadIdx.x >> 6);
    int lane = threadIdx.x & 63;
    if (node >= NN) return;
    int sub = lane / LPR;
    int li  = lane % LPR;
    int r0 = rowptr[node], r1 = rowptr[node + 1];

    float a[8] = {0.f, 0.f, 0.f, 0.f, 0.f, 0.f, 0.f, 0.f};
    float b[8] = {0.f, 0.f, 0.f, 0.f, 0.f, 0.f, 0.f, 0.f};
    int e0 = r0 + sub;
    int e1 = e0 + EPW;
    int i0 = (e0 < r1) ? csr[e0] : 0;
    int i1 = (e1 < r1) ? csr[e1] : 0;
    while (e1 < r1) {
        int e0n = e0 + 2 * EPW, e1n = e1 + 2 * EPW;
        int i0n = (e0n < r1) ? csr[e0n] : 0;
        int i1n = (e1n < r1) ? csr[e1n] : 0;
        uint4 v0 = *(const uint4*)(in + (size_t)i0 * D + li * 8);
        uint4 v1 = *(const uint4*)(in + (size_t)i1 * D + li * 8);
        a[0] += lo_f(v0.x); a[1] += hi_f(v0.x); a[2] += lo_f(v0.y); a[3] += hi_f(v0.y);
        a[4] += lo_f(v0.z); a[5] += hi_f(v0.z); a[6] += lo_f(v0.w); a[7] += hi_f(v0.w);
        b[0] += lo_f(v1.x); b[1] += hi_f(v1.x); b[2] += lo_f(v1.y); b[3] += hi_f(v1.y);
        b[4] += lo_f(v1.z); b[5] += hi_f(v1.z); b[6] += lo_f(v1.w); b[7] += hi_f(v1.w);
        e0 = e0n; e1 = e1n; i0 = i0n; i1 = i1n;
    }
    if (e0 < r1) {
        uint4 v0 = *(const uint4*)(in + (size_t)i0 * D + li * 8);
        a[0] += lo_f(v0.x); a[1] += hi_f(v0.x); a[2] += lo_f(v0.y); a[3] += hi_f(v0.y);
        a[4] += lo_f(v0.z); a[5] += hi_f(v0.z); a[6] += lo_f(v0.w); a[7] += hi_f(v0.w);
    }
    #pragma unroll
    for (int j = 0; j < 8; j++) a[j] += b[j];
    #pragma unroll
    for (int off = LPR; off < 64; off <<= 1)
        #pragma unroll
        for (int j = 0; j < 8; j++) a[j] += __shfl_xor(a[j], off, 64);
    if (sub == 0) {
        float inv = 1.0f / fmaxf((float)(r1 - r0), 1.0f);
        #pragma unroll
        for (int j = 0; j < 8; j++) a[j] *= inv;
        if (addp) {
            float4 p0 = *(const float4*)&addp[(size_t)node * addStride + li * 8];
            float4 p1 = *(const float4*)&addp[(size_t)node * addStride + li * 8 + 4];
            a[0] += p0.x; a[1] += p0.y; a[2] += p0.z; a[3] += p0.w;
            a[4] += p1.x; a[5] += p1.y; a[6] += p1.z; a[7] += p1.w;
        }
        if constexpr (OBF) {
            ushort h[8];
            #pragma unroll
            for (int j = 0; j < 8; j++) h[j] = bf16_rne(a[j]);
            *(bf16x8*)&outB[(size_t)node * D + li * 8] = *(bf16x8*)h;
        } else {
            *(float4*)&outF[(size_t)node * D + li * 8]     = make_float4(a[0], a[1], a[2], a[3]);
            *(float4*)&outF[(size_t)node * D + li * 8 + 4] = make_float4(a[4], a[5], a[6], a[7]);
        }
    }
}

// ---------------- CSR gather-mean aggregation, D=128, 4-stream ----------------

__global__ void k_aggb128(const ushort* __restrict__ in, float* __restrict__ out,
                          const int* __restrict__ rowptr, const int* __restrict__ csr) {
    constexpr int D = 128, LPR = 16, EPW = 4;
    int node = blockIdx.x * 4 + (threadIdx.x >> 6);
    int lane = threadIdx.x & 63;
    if (node >= NN) return;
    int sub = lane / LPR;
    int li  = lane % LPR;
    int r0 = rowptr[node], r1 = rowptr[node + 1];

    float a[8] = {0.f, 0.f, 0.f, 0.f, 0.f, 0.f, 0.f, 0.f};
    float b[8] = {0.f, 0.f, 0.f, 0.f, 0.f, 0.f, 0.f, 0.f};
    int e0 = r0 + sub, e1 = e0 + EPW, e2 = e0 + 2 * EPW, e3 = e0 + 3 * EPW;
    int i0 = (e0 < r1) ? csr[e0] : 0;
    int i1 = (e1 < r1) ? csr[e1] : 0;
    int i2 = (e2 < r1) ? csr[e2] : 0;
    int i3 = (e3 < r1) ? csr[e3] : 0;

#define ACC(A, V)                                                      \
    A[0] += lo_f(V.x); A[1] += hi_f(V.x); A[2] += lo_f(V.y); A[3] += hi_f(V.y); \
    A[4] += lo_f(V.z); A[5] += hi_f(V.z); A[6] += lo_f(V.w); A[7] += hi_f(V.w);

    while (e3 < r1) {
        int e0n = e0 + 16, e1n = e1 + 16, e2n = e2 + 16, e3n = e3 + 16;
        int i0n = (e0n < r1) ? csr[e0n] : 0;
        int i1n = (e1n < r1) ? csr[e1n] : 0;
        int i2n = (e2n < r1) ? csr[e2n] : 0;
        int i3n = (e3n < r1) ? csr[e3n] : 0;
        uint4 v0 = *(const uint4*)(in + (size_t)i0 * D + li * 8);
        uint4 v1 = *(const uint4*)(in + (size_t)i1 * D + li * 8);
        uint4 v2 = *(const uint4*)(in + (size_t)i2 * D + li * 8);
        uint4 v3 = *(const uint4*)(in + (size_t)i3 * D + li * 8);
        ACC(a, v0) ACC(b, v1) ACC(a, v2) ACC(b, v3)
        e0 = e0n; e1 = e1n; e2 = e2n; e3 = e3n;
        i0 = i0n; i1 = i1n; i2 = i2n; i3 = i3n;
    }
    if (e0 < r1) { uint4 v = *(const uint4*)(in + (size_t)i0 * D + li * 8); ACC(a, v) }
    if (e1 < r1) { uint4 v = *(const uint4*)(in + (size_t)i1 * D + li * 8); ACC(b, v) }
    if (e2 < r1) { uint4 v = *(const uint4*)(in + (size_t)i2 * D + li * 8); ACC(a, v) }
#undef ACC
    #pragma unroll
    for (int j = 0; j < 8; j++) a[j] += b[j];
    #pragma unroll
    for (int off = LPR; off < 64; off <<= 1)
        #pragma unroll
        for (int j = 0; j < 8; j++) a[j] += __shfl_xor(a[j], off, 64);
    if (sub == 0) {
        float inv = 1.0f / fmaxf((float)(r1 - r0), 1.0f);
        #pragma unroll
        for (int j = 0; j < 8; j++) a[j] *= inv;
        *(float4*)&out[(size_t)node * D + li * 8]     = make_float4(a[0], a[1], a[2], a[3]);
        *(float4*)&out[(size_t)node * D + li * 8 + 4] = make_float4(a[4], a[5], a[6], a[7]);
    }
}

// ---------------- MFMA GEMM, K-SPLIT across waves (frozen) ----------------
// C = (Ah+Al)@Wh (A fp32-effective via hi/lo split; W bf16).

template <int K, int KA, int NCAT, int RELU, int BFOUT>
__launch_bounds__(256, 5)
__global__ void k_mgemm(const float* __restrict__ inA, const float* __restrict__ inB,
                        const ushort* __restrict__ Whi,
                        const float* __restrict__ bias, float* __restrict__ out,
                        ushort* __restrict__ bfout) {
    constexpr int KB = K - KA;
    constexpr int NCH = K / 32;
    constexpr int NCHH = NCH / 2;
    __shared__ float sC[32][130];

    int tid = threadIdx.x;
    int wave = tid >> 6, lane = tid & 63;
    int lr  = lane & 15;
    int kg4 = lane >> 4;
    int half = wave >> 1;
    int wq   = wave & 1;
    int rbase = blockIdx.x * 32 + wq * 16;
    int row = min(rbase + lr, NN - 1);
    int rloc = wq * 16 + kg4 * 4;

    f32x4 acc[8];
    #pragma unroll
    for (int ct = 0; ct < 8; ct++) acc[ct] = (f32x4){0.f, 0.f, 0.f, 0.f};

    const ushort* baseH = Whi + (size_t)lane * 8;

    auto loadA = [&](int chunk, float4& v0, float4& v1) {
        int kg2 = chunk * 32 + kg4 * 8;
        if constexpr (NCAT) {
            v0 = *(const float4*)&inA[(size_t)row * K + kg2];
            v1 = *(const float4*)&inA[(size_t)row * K + kg2 + 4];
        } else {
            if (kg2 < KA) v0 = *(const float4*)&inA[(size_t)row * KA + kg2];
            else          v0 = *(const float4*)&inB[(size_t)row * KB + (kg2 - KA)];
            if (kg2 + 4 < KA) v1 = *(const float4*)&inA[(size_t)row * KA + kg2 + 4];
            else              v1 = *(const float4*)&inB[(size_t)row * KB + (kg2 + 4 - KA)];
        }
    };

    int c0 = half * NCHH;
    float4 aC0, aC1, aN0, aN1;
    loadA(c0, aC0, aC1);

    #pragma unroll
    for (int cc = 0; cc < NCHH; cc++) {
        int c = c0 + cc;
        if (cc + 1 < NCHH) loadA(c + 1, aN0, aN1);
        bf16x8 ah, al;
        {
            float av[8] = {aC0.x, aC0.y, aC0.z, aC0.w, aC1.x, aC1.y, aC1.z, aC1.w};
            #pragma unroll
            for (int j = 0; j < 8; j++) {
                ushort h = bf16_rne(av[j]);
                ushort l = bf16_rne(av[j] - bf16_to_f(h));
                ah[j] = (short)h;
                al[j] = (short)l;
            }
        }
        const ushort* ph = baseH + (size_t)c * 4096;
        #pragma unroll
        for (int ct = 0; ct < 8; ct++) {
            bf16x8 wh = *(const bf16x8*)(ph + ct * 512);
            acc[ct] = __builtin_amdgcn_mfma_f32_16x16x32_bf16(ah, wh, acc[ct], 0, 0, 0);
            acc[ct] = __builtin_amdgcn_mfma_f32_16x16x32_bf16(al, wh, acc[ct], 0, 0, 0);
        }
        aC0 = aN0; aC1 = aN1;
    }

    if (half == 1) {
        #pragma unroll
        for (int ct = 0; ct < 8; ct++)
            #pragma unroll
            for (int j = 0; j < 4; j++)
                sC[rloc + j][ct * 16 + lr] = acc[ct][j];
    }
    __syncthreads();
    if (half == 1) return;

    float bc[8];
    #pragma unroll
    for (int ct = 0; ct < 8; ct++) {
        int c = ct * 16 + lr;
        if constexpr (NCAT) bc[ct] = (c < 64) ? 0.f : bias[c - 64];
        else bc[ct] = bias[c];
    }
    #pragma unroll
    for (int j = 0; j < 4; j++) {
        int n = rbase + kg4 * 4 + j;
        if (n < NN) {
            float* orow = &out[(size_t)n * 128 + lr];
            #pragma unroll
            for (int ct = 0; ct < 8; ct++) {
                float v = acc[ct][j] + sC[rloc + j][ct * 16 + lr] + bc[ct];
                if (RELU) v = fmaxf(v, 0.f);
                orow[ct * 16] = v;
                if constexpr (BFOUT == 1) bfout[(size_t)n * 128 + ct * 16 + lr] = bf16_rne(v);
                if constexpr (BFOUT == 2) { if (ct < 4) bfout[(size_t)n * 64 + ct * 16 + lr] = bf16_rne(v); }
            }
        }
    }
}

// ---------------- decode (bf16 z, 8 edges/wave) ----------------

__global__ void k_decode(const int* __restrict__ eli, const ushort* __restrict__ zb,
                         float* __restrict__ out) {
    int w = blockIdx.x * 4 + (threadIdx.x >> 6);
    int lane = threadIdx.x & 63;
    int slot = lane >> 3;       // 0..7
    int li   = lane & 7;
    int ep   = slot & 1;        // endpoint 0=a, 1=b
    int e0 = w * 8 + (slot >> 1);
    int e1 = e0 + 4;
    int idx0 = (e0 < NL) ? eli[ep * NL + e0] : 0;
    int idx1 = (e1 < NL) ? eli[ep * NL + e1] : 0;
    uint4 v0 = *(const uint4*)(zb + (size_t)idx0 * 64 + li * 8);
    uint4 v1 = *(const uint4*)(zb + (size_t)idx1 * 64 + li * 8);
    uint4 p0, p1;
    p0.x = __shfl_xor((int)v0.x, 8, 64); p0.y = __shfl_xor((int)v0.y, 8, 64);
    p0.z = __shfl_xor((int)v0.z, 8, 64); p0.w = __shfl_xor((int)v0.w, 8, 64);
    p1.x = __shfl_xor((int)v1.x, 8, 64); p1.y = __shfl_xor((int)v1.y, 8, 64);
    p1.z = __shfl_xor((int)v1.z, 8, 64); p1.w = __shfl_xor((int)v1.w, 8, 64);
    float s0 = lo_f(v0.x) * lo_f(p0.x) + hi_f(v0.x) * hi_f(p0.x)
             + lo_f(v0.y) * lo_f(p0.y) + hi_f(v0.y) * hi_f(p0.y)
             + lo_f(v0.z) * lo_f(p0.z) + hi_f(v0.z) * hi_f(p0.z)
             + lo_f(v0.w) * lo_f(p0.w) + hi_f(v0.w) * hi_f(p0.w);
    float s1 = lo_f(v1.x) * lo_f(p1.x) + hi_f(v1.x) * hi_f(p1.x)
             + lo_f(v1.y) * lo_f(p1.y) + hi_f(v1.y) * hi_f(p1.y)
             + lo_f(v1.z) * lo_f(p1.z) + hi_f(v1.z) * hi_f(p1.z)
             + lo_f(v1.w) * lo_f(p1.w) + hi_f(v1.w) * hi_f(p1.w);
    #pragma unroll
    for (int off = 1; off < 8; off <<= 1) {
        s0 += __shfl_xor(s0, off, 64);
        s1 += __shfl_xor(s1, off, 64);
    }
    if (li == 0 && ep == 0) {
        if (e0 < NL) out[e0] = s0;
        if (e1 < NL) out[e1] = s1;
    }
}

// ---------------- launch ----------------

extern "C" void kernel_launch(void* const* d_in, const int* in_sizes, int n_in,
                              void* d_out, int out_size, void* d_ws, size_t ws_size,
                              hipStream_t stream) {
    const float* x   = (const float*)d_in[0];
    const int*   edge = (const int*)d_in[1];   // [2, NE]
    const int*   eli  = (const int*)d_in[2];   // [2, NL]
    const float* Wl1 = (const float*)d_in[3];
    const float* Wr1 = (const float*)d_in[4];
    const float* b1  = (const float*)d_in[5];
    const float* Wl2 = (const float*)d_in[6];
    const float* Wr2 = (const float*)d_in[7];
    const float* b2  = (const float*)d_in[8];
    const float* Wl3 = (const float*)d_in[9];
    const float* Wr3 = (const float*)d_in[10];
    const float* b3  = (const float*)d_in[11];
    float* out = (float*)d_out;

    char* w = (char*)d_ws;
    auto carve = [&](size_t bytes) {
        char* p = w;
        w += (bytes + 255) & ~(size_t)255;
        return p;
    };
    int*    rowptr = (int*)carve((NN + 1) * sizeof(int));
    int*    counts = (int*)carve(NN * sizeof(int));
    int*    rank   = (int*)carve(NE * sizeof(int));
    int*    csr    = (int*)carve(NE * sizeof(int));
    float*  M      = (float*)carve((size_t)NN * 64 * sizeof(float));   // mean1
    float*  A      = (float*)carve((size_t)NN * 128 * sizeof(float));  // h1
    float*  B      = (float*)carve((size_t)NN * 128 * sizeof(float));  // mean2, later pq
    float*  C      = (float*)carve((size_t)NN * 128 * sizeof(float));  // h2
    ushort* xb     = (ushort*)carve((size_t)NN * 64 * sizeof(ushort));  // bf16 x
    ushort* h1b    = (ushort*)carve((size_t)NN * 128 * sizeof(ushort)); // bf16 h1
    ushort* pb     = (ushort*)carve((size_t)NN * 64 * sizeof(ushort));  // bf16 p
    ushort* zb     = (ushort*)carve((size_t)NN * 64 * sizeof(ushort));  // bf16 z
    ushort* W1h    = (ushort*)carve(128 * 128 * sizeof(ushort));
    ushort* W2h    = (ushort*)carve(128 * 256 * sizeof(ushort));
    ushort* W3h    = (ushort*)carve(128 * 128 * sizeof(ushort));

    const int* src = edge;
    const int* tgt = edge + NE;

    // fused prep: counts=0 + x->bf16 + W fragment layouts (one kernel)
    k_prep<<<2015, 256, 0, stream>>>(Wl1, Wr1, Wl2, Wr2, Wl3, Wr3, x,
                                     W1h, W2h, W3h, xb, counts);

    // CSR build: count -> single-workgroup scan -> fill
    k_count<<<(NE + 255) / 256, 256, 0, stream>>>(tgt, counts, rank);
    k_scan_one<<<1, 1024, 0, stream>>>(counts, rowptr);
    k_fill<<<(NE + 255) / 256, 256, 0, stream>>>(src, tgt, rowptr, rank, csr);

    const int MG = (NN + 31) / 32;  // 1563 blocks

    // layer 1: mean1 = mean(x); h1 = relu([mean1|x]@[Wl1;Wr1]+b1)  (+h1 bf16 copy)
    k_aggb64<0><<<(NN + 3) / 4, 256, 0, stream>>>(xb, nullptr, 0, M, nullptr, rowptr, csr);
    k_mgemm<128, 64, 0, 1, 1><<<MG, 256, 0, stream>>>(M, x, W1h, b1, A, h1b);

    // layer 2: mean2 = mean(h1) [4-stream]; h2 = relu([mean2|h1]@[Wl2;Wr2]+b2)
    k_aggb128<<<(NN + 3) / 4, 256, 0, stream>>>(h1b, B, rowptr, csr);
    k_mgemm<256, 128, 0, 1, 0><<<MG, 256, 0, stream>>>(B, A, W2h, b2, C, nullptr);

    // layer 3: pq = h2 @ [Wl3 | Wr3] (+p bf16 copy); z = mean(p) + q  -> bf16 zb
    k_mgemm<128, 128, 1, 0, 2><<<MG, 256, 0, stream>>>(C, nullptr, W3h, b3, B, pb);
    k_aggb64<1><<<(NN + 3) / 4, 256, 0, stream>>>(pb, B + 64, 128, nullptr, zb, rowptr, csr);

    // decode: out[l] = dot(z[a], z[b])  (bf16 z)
    k_decode<<<(NL + 31) / 32, 256, 0, stream>>>(eli, zb, out);
}

// Round 20
// 196.013 us; speedup vs baseline: 1.2469x; 1.2469x over previous
//
#include <hip/hip_runtime.h>

#define NN 50000
#define NE 800000
#define NL 200000
#define NB_SCAN 196  // ceil(50000/256)

typedef __attribute__((ext_vector_type(8))) short bf16x8;
typedef __attribute__((ext_vector_type(4))) float f32x4;

__device__ __forceinline__ ushort bf16_rne(float f) {
    union { float f; unsigned u; } v; v.f = f;
    unsigned r = v.u + 0x7FFF + ((v.u >> 16) & 1);
    return (ushort)(r >> 16);
}
__device__ __forceinline__ float bf16_to_f(ushort h) {
    union { unsigned u; float f; } v; v.u = ((unsigned)h) << 16;
    return v.f;
}
__device__ __forceinline__ float lo_f(unsigned u) {
    union { unsigned u; float f; } v; v.u = u << 16;
    return v.f;
}
__device__ __forceinline__ float hi_f(unsigned u) {
    union { unsigned u; float f; } v; v.u = u & 0xffff0000u;
    return v.f;
}

// ---------------- fused prep: counts=0, x->bf16, W->fragment bf16 ----------------
// frag[chunk][ct][lane][j] -> W[chunk*32 + (lane>>4)*8 + j][ct*16 + (lane&15)].

template <int K, int KA, int NCAT>
__device__ __forceinline__ void wsplit_body(const float* __restrict__ W1,
                                            const float* __restrict__ W2,
                                            ushort* __restrict__ hi, int id) {
    if (id >= 128 * K) return;
    int col = id / K, k = id - col * K;
    float v;
    if constexpr (NCAT) {
        v = (col < 64) ? W1[(size_t)k * 64 + col] : W2[(size_t)k * 64 + (col - 64)];
    } else {
        v = (k < KA) ? W1[(size_t)k * 128 + col] : W2[(size_t)(k - KA) * 128 + col];
    }
    int chunk = k >> 5, kk = k & 31;
    int kg4 = kk >> 3, j = kk & 7;
    int ct = col >> 4, lr = col & 15;
    size_t dst = ((size_t)(chunk * 8 + ct) * 64 + kg4 * 16 + lr) * 8 + j;
    hi[dst] = bf16_rne(v);
}

// blocks: [0,64) W1 | [64,192) W2 | [192,256) W3 | [256,452) counts=0 | [452,2015) xcast
__global__ void k_prep(const float* __restrict__ Wl1, const float* __restrict__ Wr1,
                       const float* __restrict__ Wl2, const float* __restrict__ Wr2,
                       const float* __restrict__ Wl3, const float* __restrict__ Wr3,
                       const float* __restrict__ x,
                       ushort* __restrict__ W1h, ushort* __restrict__ W2h,
                       ushort* __restrict__ W3h, ushort* __restrict__ xb,
                       int* __restrict__ counts) {
    int b = blockIdx.x, t = threadIdx.x;
    if (b < 64) {
        wsplit_body<128, 64, 0>(Wl1, Wr1, W1h, b * 256 + t);
    } else if (b < 192) {
        wsplit_body<256, 128, 0>(Wl2, Wr2, W2h, (b - 64) * 256 + t);
    } else if (b < 256) {
        wsplit_body<128, 128, 1>(Wl3, Wr3, W3h, (b - 192) * 256 + t);
    } else if (b < 452) {
        int i = (b - 256) * 256 + t;
        if (i < NN) counts[i] = 0;
    } else {
        int i = (b - 452) * 256 + t;
        if (i >= NN * 8) return;
        float4 v0 = *(const float4*)&x[i * 8];
        float4 v1 = *(const float4*)&x[i * 8 + 4];
        ushort h[8] = {bf16_rne(v0.x), bf16_rne(v0.y), bf16_rne(v0.z), bf16_rne(v0.w),
                       bf16_rne(v1.x), bf16_rne(v1.y), bf16_rne(v1.z), bf16_rne(v1.w)};
        *(bf16x8*)&xb[i * 8] = *(bf16x8*)h;
    }
}

// ---------------- CSR build ----------------

__global__ void k_count(const int* __restrict__ tgt, int* __restrict__ counts,
                        int* __restrict__ rank) {
    int e = blockIdx.x * blockDim.x + threadIdx.x;
    if (e < NE) rank[e] = atomicAdd(&counts[tgt[e]], 1);
}

__global__ void k_scan1(const int* __restrict__ counts, int* __restrict__ bsum) {
    int i = blockIdx.x * 256 + threadIdx.x;
    int v = (i < NN) ? counts[i] : 0;
    #pragma unroll
    for (int off = 32; off; off >>= 1) v += __shfl_down(v, off, 64);
    __shared__ int ws4[4];
    int wave = threadIdx.x >> 6, lane = threadIdx.x & 63;
    if (lane == 0) ws4[wave] = v;
    __syncthreads();
    if (threadIdx.x == 0) bsum[blockIdx.x] = ws4[0] + ws4[1] + ws4[2] + ws4[3];
}

__global__ void k_scan2(int* __restrict__ bsum, int nb) {
    __shared__ int s[256];
    int t = threadIdx.x;
    int v = (t < nb) ? bsum[t] : 0;
    s[t] = v;
    __syncthreads();
    for (int off = 1; off < 256; off <<= 1) {
        int a = (t >= off) ? s[t - off] : 0;
        __syncthreads();
        s[t] += a;
        __syncthreads();
    }
    if (t < nb) bsum[t] = s[t] - v;  // exclusive
}

__global__ void k_scan3(const int* __restrict__ counts, const int* __restrict__ boff,
                        int* __restrict__ rowptr) {
    __shared__ int s[256];
    int t = threadIdx.x;
    int i = blockIdx.x * 256 + t;
    int v = (i < NN) ? counts[i] : 0;
    s[t] = v;
    __syncthreads();
    for (int off = 1; off < 256; off <<= 1) {
        int a = (t >= off) ? s[t - off] : 0;
        __syncthreads();
        s[t] += a;
        __syncthreads();
    }
    int excl = s[t] - v + boff[blockIdx.x];
    if (i < NN) rowptr[i] = excl;
    if (i == NN - 1) rowptr[NN] = excl + v;  // == NE
}

__global__ void k_fill(const int* __restrict__ src, const int* __restrict__ tgt,
                       const int* __restrict__ rowptr, const int* __restrict__ rank,
                       int* __restrict__ csr) {
    int e = blockIdx.x * blockDim.x + threadIdx.x;
    if (e < NE) csr[rowptr[tgt[e]] + rank[e]] = src[e];
}

// ---------------- CSR gather-mean aggregation, D=64, 2-stream ----------------
// OBF=0: fp32 out. OBF=1: bf16 out (+fp32 addp first).

template <int OBF>
__global__ void k_aggb64(const ushort* __restrict__ in,
                         const float* __restrict__ addp, int addStride,
                         float* __restrict__ outF, ushort* __restrict__ outB,
                         const int* __restrict__ rowptr, const int* __restrict__ csr) {
    constexpr int D = 64, LPR = 8, EPW = 8;
    int node = blockIdx.x * 4 + (threadIdx.x >> 6);
    int lane = threadIdx.x & 63;
    if (node >= NN) return;
    int sub = lane / LPR;
    int li  = lane % LPR;
    int r0 = rowptr[node], r1 = rowptr[node + 1];

    float a[8] = {0.f, 0.f, 0.f, 0.f, 0.f, 0.f, 0.f, 0.f};
    float b[8] = {0.f, 0.f, 0.f, 0.f, 0.f, 0.f, 0.f, 0.f};
    int e0 = r0 + sub;
    int e1 = e0 + EPW;
    int i0 = (e0 < r1) ? csr[e0] : 0;
    int i1 = (e1 < r1) ? csr[e1] : 0;
    while (e1 < r1) {
        int e0n = e0 + 2 * EPW, e1n = e1 + 2 * EPW;
        int i0n = (e0n < r1) ? csr[e0n] : 0;
        int i1n = (e1n < r1) ? csr[e1n] : 0;
        uint4 v0 = *(const uint4*)(in + (size_t)i0 * D + li * 8);
        uint4 v1 = *(const uint4*)(in + (size_t)i1 * D + li * 8);
        a[0] += lo_f(v0.x); a[1] += hi_f(v0.x); a[2] += lo_f(v0.y); a[3] += hi_f(v0.y);
        a[4] += lo_f(v0.z); a[5] += hi_f(v0.z); a[6] += lo_f(v0.w); a[7] += hi_f(v0.w);
        b[0] += lo_f(v1.x); b[1] += hi_f(v1.x); b[2] += lo_f(v1.y); b[3] += hi_f(v1.y);
        b[4] += lo_f(v1.z); b[5] += hi_f(v1.z); b[6] += lo_f(v1.w); b[7] += hi_f(v1.w);
        e0 = e0n; e1 = e1n; i0 = i0n; i1 = i1n;
    }
    if (e0 < r1) {
        uint4 v0 = *(const uint4*)(in + (size_t)i0 * D + li * 8);
        a[0] += lo_f(v0.x); a[1] += hi_f(v0.x); a[2] += lo_f(v0.y); a[3] += hi_f(v0.y);
        a[4] += lo_f(v0.z); a[5] += hi_f(v0.z); a[6] += lo_f(v0.w); a[7] += hi_f(v0.w);
    }
    #pragma unroll
    for (int j = 0; j < 8; j++) a[j] += b[j];
    #pragma unroll
    for (int off = LPR; off < 64; off <<= 1)
        #pragma unroll
        for (int j = 0; j < 8; j++) a[j] += __shfl_xor(a[j], off, 64);
    if (sub == 0) {
        float inv = 1.0f / fmaxf((float)(r1 - r0), 1.0f);
        #pragma unroll
        for (int j = 0; j < 8; j++) a[j] *= inv;
        if (addp) {
            float4 p0 = *(const float4*)&addp[(size_t)node * addStride + li * 8];
            float4 p1 = *(const float4*)&addp[(size_t)node * addStride + li * 8 + 4];
            a[0] += p0.x; a[1] += p0.y; a[2] += p0.z; a[3] += p0.w;
            a[4] += p1.x; a[5] += p1.y; a[6] += p1.z; a[7] += p1.w;
        }
        if constexpr (OBF) {
            ushort h[8];
            #pragma unroll
            for (int j = 0; j < 8; j++) h[j] = bf16_rne(a[j]);
            *(bf16x8*)&outB[(size_t)node * D + li * 8] = *(bf16x8*)h;
        } else {
            *(float4*)&outF[(size_t)node * D + li * 8]     = make_float4(a[0], a[1], a[2], a[3]);
            *(float4*)&outF[(size_t)node * D + li * 8 + 4] = make_float4(a[4], a[5], a[6], a[7]);
        }
    }
}

// ---------------- CSR gather-mean aggregation, D=128, 4-stream ----------------

__global__ void k_aggb128(const ushort* __restrict__ in, float* __restrict__ out,
                          const int* __restrict__ rowptr, const int* __restrict__ csr) {
    constexpr int D = 128, LPR = 16, EPW = 4;
    int node = blockIdx.x * 4 + (threadIdx.x >> 6);
    int lane = threadIdx.x & 63;
    if (node >= NN) return;
    int sub = lane / LPR;
    int li  = lane % LPR;
    int r0 = rowptr[node], r1 = rowptr[node + 1];

    float a[8] = {0.f, 0.f, 0.f, 0.f, 0.f, 0.f, 0.f, 0.f};
    float b[8] = {0.f, 0.f, 0.f, 0.f, 0.f, 0.f, 0.f, 0.f};
    int e0 = r0 + sub, e1 = e0 + EPW, e2 = e0 + 2 * EPW, e3 = e0 + 3 * EPW;
    int i0 = (e0 < r1) ? csr[e0] : 0;
    int i1 = (e1 < r1) ? csr[e1] : 0;
    int i2 = (e2 < r1) ? csr[e2] : 0;
    int i3 = (e3 < r1) ? csr[e3] : 0;

#define ACC(A, V)                                                      \
    A[0] += lo_f(V.x); A[1] += hi_f(V.x); A[2] += lo_f(V.y); A[3] += hi_f(V.y); \
    A[4] += lo_f(V.z); A[5] += hi_f(V.z); A[6] += lo_f(V.w); A[7] += hi_f(V.w);

    while (e3 < r1) {
        int e0n = e0 + 16, e1n = e1 + 16, e2n = e2 + 16, e3n = e3 + 16;
        int i0n = (e0n < r1) ? csr[e0n] : 0;
        int i1n = (e1n < r1) ? csr[e1n] : 0;
        int i2n = (e2n < r1) ? csr[e2n] : 0;
        int i3n = (e3n < r1) ? csr[e3n] : 0;
        uint4 v0 = *(const uint4*)(in + (size_t)i0 * D + li * 8);
        uint4 v1 = *(const uint4*)(in + (size_t)i1 * D + li * 8);
        uint4 v2 = *(const uint4*)(in + (size_t)i2 * D + li * 8);
        uint4 v3 = *(const uint4*)(in + (size_t)i3 * D + li * 8);
        ACC(a, v0) ACC(b, v1) ACC(a, v2) ACC(b, v3)
        e0 = e0n; e1 = e1n; e2 = e2n; e3 = e3n;
        i0 = i0n; i1 = i1n; i2 = i2n; i3 = i3n;
    }
    if (e0 < r1) { uint4 v = *(const uint4*)(in + (size_t)i0 * D + li * 8); ACC(a, v) }
    if (e1 < r1) { uint4 v = *(const uint4*)(in + (size_t)i1 * D + li * 8); ACC(b, v) }
    if (e2 < r1) { uint4 v = *(const uint4*)(in + (size_t)i2 * D + li * 8); ACC(a, v) }
#undef ACC
    #pragma unroll
    for (int j = 0; j < 8; j++) a[j] += b[j];
    #pragma unroll
    for (int off = LPR; off < 64; off <<= 1)
        #pragma unroll
        for (int j = 0; j < 8; j++) a[j] += __shfl_xor(a[j], off, 64);
    if (sub == 0) {
        float inv = 1.0f / fmaxf((float)(r1 - r0), 1.0f);
        #pragma unroll
        for (int j = 0; j < 8; j++) a[j] *= inv;
        *(float4*)&out[(size_t)node * D + li * 8]     = make_float4(a[0], a[1], a[2], a[3]);
        *(float4*)&out[(size_t)node * D + li * 8 + 4] = make_float4(a[4], a[5], a[6], a[7]);
    }
}

// ---------------- MFMA GEMM, K-SPLIT across waves (frozen) ----------------
// C = (Ah+Al)@Wh (A fp32-effective via hi/lo split; W bf16).

template <int K, int KA, int NCAT, int RELU, int BFOUT>
__launch_bounds__(256, 5)
__global__ void k_mgemm(const float* __restrict__ inA, const float* __restrict__ inB,
                        const ushort* __restrict__ Whi,
                        const float* __restrict__ bias, float* __restrict__ out,
                        ushort* __restrict__ bfout) {
    constexpr int KB = K - KA;
    constexpr int NCH = K / 32;
    constexpr int NCHH = NCH / 2;
    __shared__ float sC[32][130];

    int tid = threadIdx.x;
    int wave = tid >> 6, lane = tid & 63;
    int lr  = lane & 15;
    int kg4 = lane >> 4;
    int half = wave >> 1;
    int wq   = wave & 1;
    int rbase = blockIdx.x * 32 + wq * 16;
    int row = min(rbase + lr, NN - 1);
    int rloc = wq * 16 + kg4 * 4;

    f32x4 acc[8];
    #pragma unroll
    for (int ct = 0; ct < 8; ct++) acc[ct] = (f32x4){0.f, 0.f, 0.f, 0.f};

    const ushort* baseH = Whi + (size_t)lane * 8;

    auto loadA = [&](int chunk, float4& v0, float4& v1) {
        int kg2 = chunk * 32 + kg4 * 8;
        if constexpr (NCAT) {
            v0 = *(const float4*)&inA[(size_t)row * K + kg2];
            v1 = *(const float4*)&inA[(size_t)row * K + kg2 + 4];
        } else {
            if (kg2 < KA) v0 = *(const float4*)&inA[(size_t)row * KA + kg2];
            else          v0 = *(const float4*)&inB[(size_t)row * KB + (kg2 - KA)];
            if (kg2 + 4 < KA) v1 = *(const float4*)&inA[(size_t)row * KA + kg2 + 4];
            else              v1 = *(const float4*)&inB[(size_t)row * KB + (kg2 + 4 - KA)];
        }
    };

    int c0 = half * NCHH;
    float4 aC0, aC1, aN0, aN1;
    loadA(c0, aC0, aC1);

    #pragma unroll
    for (int cc = 0; cc < NCHH; cc++) {
        int c = c0 + cc;
        if (cc + 1 < NCHH) loadA(c + 1, aN0, aN1);
        bf16x8 ah, al;
        {
            float av[8] = {aC0.x, aC0.y, aC0.z, aC0.w, aC1.x, aC1.y, aC1.z, aC1.w};
            #pragma unroll
            for (int j = 0; j < 8; j++) {
                ushort h = bf16_rne(av[j]);
                ushort l = bf16_rne(av[j] - bf16_to_f(h));
                ah[j] = (short)h;
                al[j] = (short)l;
            }
        }
        const ushort* ph = baseH + (size_t)c * 4096;
        #pragma unroll
        for (int ct = 0; ct < 8; ct++) {
            bf16x8 wh = *(const bf16x8*)(ph + ct * 512);
            acc[ct] = __builtin_amdgcn_mfma_f32_16x16x32_bf16(ah, wh, acc[ct], 0, 0, 0);
            acc[ct] = __builtin_amdgcn_mfma_f32_16x16x32_bf16(al, wh, acc[ct], 0, 0, 0);
        }
        aC0 = aN0; aC1 = aN1;
    }

    if (half == 1) {
        #pragma unroll
        for (int ct = 0; ct < 8; ct++)
            #pragma unroll
            for (int j = 0; j < 4; j++)
                sC[rloc + j][ct * 16 + lr] = acc[ct][j];
    }
    __syncthreads();
    if (half == 1) return;

    float bc[8];
    #pragma unroll
    for (int ct = 0; ct < 8; ct++) {
        int c = ct * 16 + lr;
        if constexpr (NCAT) bc[ct] = (c < 64) ? 0.f : bias[c - 64];
        else bc[ct] = bias[c];
    }
    #pragma unroll
    for (int j = 0; j < 4; j++) {
        int n = rbase + kg4 * 4 + j;
        if (n < NN) {
            float* orow = &out[(size_t)n * 128 + lr];
            #pragma unroll
            for (int ct = 0; ct < 8; ct++) {
                float v = acc[ct][j] + sC[rloc + j][ct * 16 + lr] + bc[ct];
                if (RELU) v = fmaxf(v, 0.f);
                orow[ct * 16] = v;
                if constexpr (BFOUT == 1) bfout[(size_t)n * 128 + ct * 16 + lr] = bf16_rne(v);
                if constexpr (BFOUT == 2) { if (ct < 4) bfout[(size_t)n * 64 + ct * 16 + lr] = bf16_rne(v); }
            }
        }
    }
}

// ---------------- decode (bf16 z, 8 edges/wave) ----------------

__global__ void k_decode(const int* __restrict__ eli, const ushort* __restrict__ zb,
                         float* __restrict__ out) {
    int w = blockIdx.x * 4 + (threadIdx.x >> 6);
    int lane = threadIdx.x & 63;
    int slot = lane >> 3;       // 0..7
    int li   = lane & 7;
    int ep   = slot & 1;        // endpoint 0=a, 1=b
    int e0 = w * 8 + (slot >> 1);
    int e1 = e0 + 4;
    int idx0 = (e0 < NL) ? eli[ep * NL + e0] : 0;
    int idx1 = (e1 < NL) ? eli[ep * NL + e1] : 0;
    uint4 v0 = *(const uint4*)(zb + (size_t)idx0 * 64 + li * 8);
    uint4 v1 = *(const uint4*)(zb + (size_t)idx1 * 64 + li * 8);
    uint4 p0, p1;
    p0.x = __shfl_xor((int)v0.x, 8, 64); p0.y = __shfl_xor((int)v0.y, 8, 64);
    p0.z = __shfl_xor((int)v0.z, 8, 64); p0.w = __shfl_xor((int)v0.w, 8, 64);
    p1.x = __shfl_xor((int)v1.x, 8, 64); p1.y = __shfl_xor((int)v1.y, 8, 64);
    p1.z = __shfl_xor((int)v1.z, 8, 64); p1.w = __shfl_xor((int)v1.w, 8, 64);
    float s0 = lo_f(v0.x) * lo_f(p0.x) + hi_f(v0.x) * hi_f(p0.x)
             + lo_f(v0.y) * lo_f(p0.y) + hi_f(v0.y) * hi_f(p0.y)
             + lo_f(v0.z) * lo_f(p0.z) + hi_f(v0.z) * hi_f(p0.z)
             + lo_f(v0.w) * lo_f(p0.w) + hi_f(v0.w) * hi_f(p0.w);
    float s1 = lo_f(v1.x) * lo_f(p1.x) + hi_f(v1.x) * hi_f(p1.x)
             + lo_f(v1.y) * lo_f(p1.y) + hi_f(v1.y) * hi_f(p1.y)
             + lo_f(v1.z) * lo_f(p1.z) + hi_f(v1.z) * hi_f(p1.z)
             + lo_f(v1.w) * lo_f(p1.w) + hi_f(v1.w) * hi_f(p1.w);
    #pragma unroll
    for (int off = 1; off < 8; off <<= 1) {
        s0 += __shfl_xor(s0, off, 64);
        s1 += __shfl_xor(s1, off, 64);
    }
    if (li == 0 && ep == 0) {
        if (e0 < NL) out[e0] = s0;
        if (e1 < NL) out[e1] = s1;
    }
}

// ---------------- launch ----------------

extern "C" void kernel_launch(void* const* d_in, const int* in_sizes, int n_in,
                              void* d_out, int out_size, void* d_ws, size_t ws_size,
                              hipStream_t stream) {
    const float* x   = (const float*)d_in[0];
    const int*   edge = (const int*)d_in[1];   // [2, NE]
    const int*   eli  = (const int*)d_in[2];   // [2, NL]
    const float* Wl1 = (const float*)d_in[3];
    const float* Wr1 = (const float*)d_in[4];
    const float* b1  = (const float*)d_in[5];
    const float* Wl2 = (const float*)d_in[6];
    const float* Wr2 = (const float*)d_in[7];
    const float* b2  = (const float*)d_in[8];
    const float* Wl3 = (const float*)d_in[9];
    const float* Wr3 = (const float*)d_in[10];
    const float* b3  = (const float*)d_in[11];
    float* out = (float*)d_out;

    char* w = (char*)d_ws;
    auto carve = [&](size_t bytes) {
        char* p = w;
        w += (bytes + 255) & ~(size_t)255;
        return p;
    };
    int*    rowptr = (int*)carve((NN + 1) * sizeof(int));
    int*    counts = (int*)carve(NN * sizeof(int));
    int*    rank   = (int*)carve(NE * sizeof(int));
    int*    csr    = (int*)carve(NE * sizeof(int));
    int*    bsum   = (int*)carve(256 * sizeof(int));
    float*  M      = (float*)carve((size_t)NN * 64 * sizeof(float));   // mean1
    float*  A      = (float*)carve((size_t)NN * 128 * sizeof(float));  // h1
    float*  B      = (float*)carve((size_t)NN * 128 * sizeof(float));  // mean2, later pq
    float*  C      = (float*)carve((size_t)NN * 128 * sizeof(float));  // h2
    ushort* xb     = (ushort*)carve((size_t)NN * 64 * sizeof(ushort));  // bf16 x
    ushort* h1b    = (ushort*)carve((size_t)NN * 128 * sizeof(ushort)); // bf16 h1
    ushort* pb     = (ushort*)carve((size_t)NN * 64 * sizeof(ushort));  // bf16 p
    ushort* zb     = (ushort*)carve((size_t)NN * 64 * sizeof(ushort));  // bf16 z
    ushort* W1h    = (ushort*)carve(128 * 128 * sizeof(ushort));
    ushort* W2h    = (ushort*)carve(128 * 256 * sizeof(ushort));
    ushort* W3h    = (ushort*)carve(128 * 128 * sizeof(ushort));

    const int* src = edge;
    const int* tgt = edge + NE;

    // fused prep: counts=0 + x->bf16 + W fragment layouts (one kernel)
    k_prep<<<2015, 256, 0, stream>>>(Wl1, Wr1, Wl2, Wr2, Wl3, Wr3, x,
                                     W1h, W2h, W3h, xb, counts);

    // CSR build: count -> 3-kernel scan -> fill
    k_count<<<(NE + 255) / 256, 256, 0, stream>>>(tgt, counts, rank);
    k_scan1<<<NB_SCAN, 256, 0, stream>>>(counts, bsum);
    k_scan2<<<1, 256, 0, stream>>>(bsum, NB_SCAN);
    k_scan3<<<NB_SCAN, 256, 0, stream>>>(counts, bsum, rowptr);
    k_fill<<<(NE + 255) / 256, 256, 0, stream>>>(src, tgt, rowptr, rank, csr);

    const int MG = (NN + 31) / 32;  // 1563 blocks

    // layer 1: mean1 = mean(x); h1 = relu([mean1|x]@[Wl1;Wr1]+b1)  (+h1 bf16 copy)
    k_aggb64<0><<<(NN + 3) / 4, 256, 0, stream>>>(xb, nullptr, 0, M, nullptr, rowptr, csr);
    k_mgemm<128, 64, 0, 1, 1><<<MG, 256, 0, stream>>>(M, x, W1h, b1, A, h1b);

    // layer 2: mean2 = mean(h1) [4-stream]; h2 = relu([mean2|h1]@[Wl2;Wr2]+b2)
    k_aggb128<<<(NN + 3) / 4, 256, 0, stream>>>(h1b, B, rowptr, csr);
    k_mgemm<256, 128, 0, 1, 0><<<MG, 256, 0, stream>>>(B, A, W2h, b2, C, nullptr);

    // layer 3: pq = h2 @ [Wl3 | Wr3] (+p bf16 copy); z = mean(p) + q  -> bf16 zb
    k_mgemm<128, 128, 1, 0, 2><<<MG, 256, 0, stream>>>(C, nullptr, W3h, b3, B, pb);
    k_aggb64<1><<<(NN + 3) / 4, 256, 0, stream>>>(pb, B + 64, 128, nullptr, zb, rowptr, csr);

    // decode: out[l] = dot(z[a], z[b])  (bf16 z)
    k_decode<<<(NL + 31) / 32, 256, 0, stream>>>(eli, zb, out);
}